// Round 2
// baseline (856.849 us; speedup 1.0000x reference)
//
#include <hip/hip_runtime.h>
#include <hip/hip_bf16.h>

// Problem constants
#define B_  2
#define T_  2048
#define D_  1024
#define H_  16
#define DH_ 64
#define M_  (B_*T_)      // 4096 rows for the big GEMMs

typedef __bf16 bf16;
typedef __bf16 bf16x8 __attribute__((ext_vector_type(8)));
typedef __bf16 bf16x4 __attribute__((ext_vector_type(4)));
typedef float  f32x4  __attribute__((ext_vector_type(4)));

// 0.125 (1/sqrt(64)) * log2(e): exp(s*0.125) == exp2(s*SCL2)
#define SCL2 0.18033688011112042f

// async global->LDS, 16B per lane; lds base must be wave-uniform
#define GLD16(g, l) __builtin_amdgcn_global_load_lds( \
    (const __attribute__((address_space(1))) void*)(g), \
    (__attribute__((address_space(3))) void*)(l), 16, 0, 0)

// ---------------------------------------------------------------------------
// LayerNorm: one block per row (1024 floats), 3 sources selected by blockIdx.y
// ---------------------------------------------------------------------------
__global__ __launch_bounds__(256) void ln_kernel(
    const float* __restrict__ xq, const float* __restrict__ xk,
    const float* __restrict__ xv, const float* __restrict__ gamma,
    const float* __restrict__ beta,
    bf16* __restrict__ oq, bf16* __restrict__ ok, bf16* __restrict__ ov)
{
    const int row = blockIdx.x;
    const int sel = blockIdx.y;
    const float* x = (sel == 0 ? xq : sel == 1 ? xk : xv) + (size_t)row * D_;
    bf16*        o = (sel == 0 ? oq : sel == 1 ? ok : ov) + (size_t)row * D_;
    const int tid = threadIdx.x;

    float4 v = *(const float4*)&x[tid * 4];
    float s  = v.x + v.y + v.z + v.w;
    float s2 = v.x*v.x + v.y*v.y + v.z*v.z + v.w*v.w;
    for (int off = 32; off > 0; off >>= 1) {
        s  += __shfl_down(s,  off, 64);
        s2 += __shfl_down(s2, off, 64);
    }
    __shared__ float red[8];
    const int wave = tid >> 6, lane = tid & 63;
    if (lane == 0) { red[wave] = s; red[4 + wave] = s2; }
    __syncthreads();
    s  = red[0] + red[1] + red[2] + red[3];
    s2 = red[4] + red[5] + red[6] + red[7];
    const float mu   = s * (1.0f / D_);
    const float var  = s2 * (1.0f / D_) - mu * mu;
    const float rstd = rsqrtf(var + 1e-5f);

    float4 g  = *(const float4*)&gamma[tid * 4];
    float4 bb = *(const float4*)&beta[tid * 4];
    bf16x4 o4;
    o4[0] = (bf16)((v.x - mu) * rstd * g.x + bb.x);
    o4[1] = (bf16)((v.y - mu) * rstd * g.y + bb.y);
    o4[2] = (bf16)((v.z - mu) * rstd * g.z + bb.z);
    o4[3] = (bf16)((v.w - mu) * rstd * g.w + bb.w);
    *(bf16x4*)&o[tid * 4] = o4;
}

// ---------------------------------------------------------------------------
// Weight convert + transpose: W[k][n] fp32 -> Wt[n][k] bf16 (1024x1024 each)
// ---------------------------------------------------------------------------
__global__ __launch_bounds__(256) void wconv_kernel(
    const float* __restrict__ Wq, const float* __restrict__ Wk,
    const float* __restrict__ Wv, const float* __restrict__ Wo,
    bf16* __restrict__ wqt, bf16* __restrict__ wkt,
    bf16* __restrict__ wvt, bf16* __restrict__ wot)
{
    const float* Ws[4] = {Wq, Wk, Wv, Wo};
    bf16*        Wt[4] = {wqt, wkt, wvt, wot};
    const float* W = Ws[blockIdx.z];
    bf16*        O = Wt[blockIdx.z];
    const int n0 = blockIdx.x * 32, k0 = blockIdx.y * 32;
    __shared__ float tile[32][33];
    const int tid = threadIdx.x;
    #pragma unroll
    for (int i = 0; i < 4; i++) {
        int e = tid + i * 256;
        int r = e >> 5, c = e & 31;
        tile[r][c] = W[(size_t)(k0 + r) * 1024 + n0 + c];
    }
    __syncthreads();
    #pragma unroll
    for (int i = 0; i < 4; i++) {
        int e = tid + i * 256;
        int nr = e >> 5, kc = e & 31;
        O[(size_t)(n0 + nr) * 1024 + k0 + kc] = (bf16)tile[kc][nr];
    }
}

// ---------------------------------------------------------------------------
// V head transpose: Vh [bh][t][dh] -> VhT [bh][dh][t]  (64x64 tiles via LDS)
// ---------------------------------------------------------------------------
__global__ __launch_bounds__(256) void vtrans_kernel(
    const bf16* __restrict__ Vh, bf16* __restrict__ VhT)
{
    const int bh = blockIdx.y, t0 = blockIdx.x * 64;
    const bf16* src = Vh  + (size_t)bh * T_ * DH_;
    bf16*       dst = VhT + (size_t)bh * T_ * DH_;
    __shared__ bf16 tile[64][72];
    const int tid = threadIdx.x;
    const int r = tid >> 3, c8 = (tid & 7) * 8;
    *(bf16x8*)&tile[r][c8]      = *(const bf16x8*)&src[(size_t)(t0 + r) * DH_ + c8];
    *(bf16x8*)&tile[32 + r][c8] = *(const bf16x8*)&src[(size_t)(t0 + 32 + r) * DH_ + c8];
    __syncthreads();
    bf16x8 o0, o1;
    #pragma unroll
    for (int j = 0; j < 8; j++) { o0[j] = tile[c8 + j][r]; o1[j] = tile[c8 + j][32 + r]; }
    *(bf16x8*)&dst[(size_t)r * T_ + t0 + c8]        = o0;
    *(bf16x8*)&dst[(size_t)(32 + r) * T_ + t0 + c8] = o1;
}

// ---------------------------------------------------------------------------
// GEMM: C[M,N] = A[M,K] @ Bt[N,K]^T + bias.  M=4096, N=K=1024.
// m97 structure: global_load_lds width-16 into unpadded [128][32] LDS tiles.
// MODE 0: headed bf16 output [B][H][T][DH];  MODE 1: row-major fp32 output.
// ---------------------------------------------------------------------------
template <int MODE>
__global__ __launch_bounds__(256) void gemm_bt(
    const bf16* __restrict__ A, const bf16* __restrict__ Bt,
    const float* __restrict__ bias, void* __restrict__ Cout)
{
    __shared__ bf16 sA[128][32];
    __shared__ bf16 sB[128][32];
    const int tid  = threadIdx.x;
    const int wave = tid >> 6, lane = tid & 63;
    const int quad = lane >> 4, l16 = lane & 15;
    const int wr = (wave >> 1) * 64, wc = (wave & 1) * 64;
    const int m0 = blockIdx.y * 128, n0 = blockIdx.x * 128;

    f32x4 acc[4][4] = {};

    // staging: wave w covers rows [w*32, w*32+32) in 2 instrs of 1KB each
    const int srow = wave * 32 + (lane >> 2);   // +0 / +16
    const int scol = (lane & 3) * 8;
    const bf16* gA0 = &A [(size_t)(m0 + srow)      * 1024 + scol];
    const bf16* gA1 = &A [(size_t)(m0 + srow + 16) * 1024 + scol];
    const bf16* gB0 = &Bt[(size_t)(n0 + srow)      * 1024 + scol];
    const bf16* gB1 = &Bt[(size_t)(n0 + srow + 16) * 1024 + scol];
    bf16* lA0 = &sA[wave * 32][0];
    bf16* lA1 = &sA[wave * 32 + 16][0];
    bf16* lB0 = &sB[wave * 32][0];
    bf16* lB1 = &sB[wave * 32 + 16][0];

    for (int k0 = 0; k0 < 1024; k0 += 32) {
        __syncthreads();
        GLD16(gA0 + k0, lA0);
        GLD16(gA1 + k0, lA1);
        GLD16(gB0 + k0, lB0);
        GLD16(gB1 + k0, lB1);
        __syncthreads();   // compiler emits vmcnt(0) drain before s_barrier

        bf16x8 af[4], bfr[4];
        #pragma unroll
        for (int i = 0; i < 4; i++) af[i]  = *(bf16x8*)&sA[wr + i * 16 + l16][quad * 8];
        #pragma unroll
        for (int j = 0; j < 4; j++) bfr[j] = *(bf16x8*)&sB[wc + j * 16 + l16][quad * 8];
        #pragma unroll
        for (int i = 0; i < 4; i++)
            #pragma unroll
            for (int j = 0; j < 4; j++)
                acc[i][j] = __builtin_amdgcn_mfma_f32_16x16x32_bf16(af[i], bfr[j], acc[i][j], 0, 0, 0);
    }

    #pragma unroll
    for (int i = 0; i < 4; i++) {
        #pragma unroll
        for (int j = 0; j < 4; j++) {
            const int n = n0 + wc + j * 16 + l16;
            const float bia = bias[n];
            #pragma unroll
            for (int r = 0; r < 4; r++) {
                const int m = m0 + wr + i * 16 + quad * 4 + r;
                const float v = acc[i][j][r] + bia;
                if (MODE == 0) {
                    const int b = m >> 11, t = m & 2047, h = n >> 6, dh = n & 63;
                    ((bf16*)Cout)[(((size_t)b * H_ + h) * T_ + t) * DH_ + dh] = (bf16)v;
                } else {
                    ((float*)Cout)[(size_t)m * 1024 + n] = v;
                }
            }
        }
    }
}

// ---------------------------------------------------------------------------
// Fused attention — barrier-free. Two sweeps per 64-query block.
// K/V^T B-fragments loaded directly from global (L1-broadcast across waves).
// Sweep 1: lsum[r] += exp2(s*SCL2) (no max; scores are O(1), safe in fp32);
//          single cross-lane reduction after the loop.
// Sweep 2: recompute S, p = exp2(s*SCL2)*linv -> Pf (per-wave fp32 LDS),
//          read back as (a) bf16 A-fragments for P@V MFMA, (b) coalesced
//          float4 rows for the 512MB attn output.
// ---------------------------------------------------------------------------
__global__ __launch_bounds__(256) void attn_kernel(
    const bf16* __restrict__ Qh, const bf16* __restrict__ Kh,
    const bf16* __restrict__ VhT, const int* __restrict__ lens,
    float* __restrict__ attn_out, bf16* __restrict__ Obuf)
{
    const int bh = blockIdx.y;
    const int b = bh >> 4, h = bh & 15;
    const int bx = blockIdx.x;
    const int q0 = bx * 64;
    const int len = lens[b];
    const bf16* Qp = Qh  + (size_t)bh * T_ * DH_;
    const bf16* Kp = Kh  + (size_t)bh * T_ * DH_;
    const bf16* Vp = VhT + (size_t)bh * T_ * DH_;   // [dh][t]
    float* attnp = attn_out + (size_t)bh * T_ * T_;

    const int tid  = threadIdx.x;
    const int wave = tid >> 6, lane = tid & 63;
    const int quad = lane >> 4, l16 = lane & 15;

    __shared__ float Pf[4][16][68];   // per-wave P tile [q][key], stride 68

    // Q fragments (A-operand: m=l16, k=quad*8+j)
    const int qrow = q0 + wave * 16 + l16;
    const bf16x8 aq0 = *(const bf16x8*)&Qp[(size_t)qrow * DH_ + quad * 8];
    const bf16x8 aq1 = *(const bf16x8*)&Qp[(size_t)qrow * DH_ + 32 + quad * 8];

    const int jb_hi = min(bx, (len - 1) >> 6);

    float lsum[4] = {0.f, 0.f, 0.f, 0.f};

    // ---------------- Sweep 1: denominators ----------------
    for (int jb = 0; jb <= jb_hi; jb++) {
        f32x4 sc[4];
        #pragma unroll
        for (int c = 0; c < 4; c++) {
            const size_t krow = (size_t)(jb * 64 + c * 16 + l16) * DH_;
            bf16x8 b0 = *(const bf16x8*)&Kp[krow + quad * 8];
            bf16x8 b1 = *(const bf16x8*)&Kp[krow + 32 + quad * 8];
            f32x4 s = {};
            s = __builtin_amdgcn_mfma_f32_16x16x32_bf16(aq0, b0, s, 0, 0, 0);
            s = __builtin_amdgcn_mfma_f32_16x16x32_bf16(aq1, b1, s, 0, 0, 0);
            sc[c] = s;
        }
        if ((jb < bx) && ((jb + 1) * 64 <= len)) {      // fully valid tile
            #pragma unroll
            for (int c = 0; c < 4; c++)
                #pragma unroll
                for (int r = 0; r < 4; r++)
                    lsum[r] += __builtin_amdgcn_exp2f(sc[c][r] * SCL2);
        } else {                                        // diagonal / length edge
            #pragma unroll
            for (int c = 0; c < 4; c++) {
                const int k_g = jb * 64 + c * 16 + l16;
                #pragma unroll
                for (int r = 0; r < 4; r++) {
                    const int t_g = q0 + wave * 16 + quad * 4 + r;
                    const bool valid = (k_g <= t_g) & (k_g < len);
                    lsum[r] += valid ? __builtin_amdgcn_exp2f(sc[c][r] * SCL2) : 0.0f;
                }
            }
        }
    }
    // one reduction over the 16 key-lanes (l16 groups are shfl-width-16 groups)
    float linv[4];
    #pragma unroll
    for (int r = 0; r < 4; r++) {
        float v = lsum[r];
        #pragma unroll
        for (int o = 1; o < 16; o <<= 1) v += __shfl_xor(v, o, 16);
        linv[r] = 1.0f / v;
    }

    // ---------------- Sweep 2: attn write + P@V ----------------
    f32x4 oacc[4] = {};
    for (int jb = 0; jb <= jb_hi; jb++) {
        f32x4 sc[4];
        #pragma unroll
        for (int c = 0; c < 4; c++) {
            const size_t krow = (size_t)(jb * 64 + c * 16 + l16) * DH_;
            bf16x8 b0 = *(const bf16x8*)&Kp[krow + quad * 8];
            bf16x8 b1 = *(const bf16x8*)&Kp[krow + 32 + quad * 8];
            f32x4 s = {};
            s = __builtin_amdgcn_mfma_f32_16x16x32_bf16(aq0, b0, s, 0, 0, 0);
            s = __builtin_amdgcn_mfma_f32_16x16x32_bf16(aq1, b1, s, 0, 0, 0);
            sc[c] = s;
        }
        const bool fullt = (jb < bx) && ((jb + 1) * 64 <= len);
        #pragma unroll
        for (int c = 0; c < 4; c++) {
            const int k_g = jb * 64 + c * 16 + l16;
            #pragma unroll
            for (int r = 0; r < 4; r++) {
                float p = __builtin_amdgcn_exp2f(sc[c][r] * SCL2) * linv[r];
                if (!fullt) {
                    const int t_g = q0 + wave * 16 + quad * 4 + r;
                    if (!((k_g <= t_g) & (k_g < len))) p = 0.0f;
                }
                Pf[wave][quad * 4 + r][c * 16 + l16] = p;
            }
        }
        asm volatile("s_waitcnt lgkmcnt(0)" ::: "memory");  // wave-local Pf visibility

        // P@V: A-frags from Pf (fp32->bf16), B-frags direct from global V^T
        #pragma unroll
        for (int ks = 0; ks < 2; ks++) {
            f32x4 p0 = *(f32x4*)&Pf[wave][l16][ks * 32 + quad * 8];
            f32x4 p1 = *(f32x4*)&Pf[wave][l16][ks * 32 + quad * 8 + 4];
            bf16x8 ap;
            ap[0] = (bf16)p0[0]; ap[1] = (bf16)p0[1]; ap[2] = (bf16)p0[2]; ap[3] = (bf16)p0[3];
            ap[4] = (bf16)p1[0]; ap[5] = (bf16)p1[1]; ap[6] = (bf16)p1[2]; ap[7] = (bf16)p1[3];
            #pragma unroll
            for (int c = 0; c < 4; c++) {
                const bf16x8 vb = *(const bf16x8*)&Vp[(size_t)(c * 16 + l16) * T_ + jb * 64 + ks * 32 + quad * 8];
                oacc[c] = __builtin_amdgcn_mfma_f32_16x16x32_bf16(ap, vb, oacc[c], 0, 0, 0);
            }
        }

        // coalesced attn store: 4 instrs x (4 rows x 256B)
        #pragma unroll
        for (int s = 0; s < 4; s++) {
            const int row = s * 4 + (lane >> 4);
            const int c4  = (lane & 15) * 4;
            f32x4 v4 = *(f32x4*)&Pf[wave][row][c4];
            *(f32x4*)&attnp[(size_t)(q0 + wave * 16 + row) * T_ + jb * 64 + c4] = v4;
        }
    }

    // Zero-fill columns beyond the last computed key tile (coalesced float4)
    const int zc0 = (jb_hi + 1) * 64;
    if (zc0 < T_) {
        const int span4 = (T_ - zc0) >> 2;
        for (int r = 0; r < 16; r++) {
            const size_t rowbase = (size_t)(q0 + wave * 16 + r) * T_ + zc0;
            for (int c4 = lane; c4 < span4; c4 += 64) {
                *(float4*)&attnp[rowbase + (size_t)c4 * 4] = make_float4(0.f, 0.f, 0.f, 0.f);
            }
        }
    }

    // O (bf16) in [b][t][h*64+dh] layout for the output GEMM
    #pragma unroll
    for (int c = 0; c < 4; c++) {
        #pragma unroll
        for (int r = 0; r < 4; r++) {
            const int t_g = q0 + wave * 16 + quad * 4 + r;
            const int dh = c * 16 + l16;
            Obuf[(size_t)(b * T_ + t_g) * 1024 + h * DH_ + dh] = (bf16)oacc[c][r];
        }
    }
}

// ---------------------------------------------------------------------------
extern "C" void kernel_launch(void* const* d_in, const int* in_sizes, int n_in,
                              void* d_out, int out_size, void* d_ws, size_t ws_size,
                              hipStream_t stream)
{
    const float* xq    = (const float*)d_in[0];
    const float* xk    = (const float*)d_in[1];
    const float* xv    = (const float*)d_in[2];
    const int*   lens  = (const int*)d_in[3];
    const float* Wq    = (const float*)d_in[4];
    const float* bq    = (const float*)d_in[5];
    const float* Wk    = (const float*)d_in[6];
    const float* bk    = (const float*)d_in[7];
    const float* Wv    = (const float*)d_in[8];
    const float* bv    = (const float*)d_in[9];
    const float* Wo    = (const float*)d_in[10];
    const float* bo    = (const float*)d_in[11];
    const float* gamma = (const float*)d_in[12];
    const float* beta  = (const float*)d_in[13];

    float* out      = (float*)d_out;
    float* attn_out = out + (size_t)M_ * D_;   // attn_viz region [B*H][T][T]

    // workspace carve-up (64 MB total; VhT aliases lnq which is dead post-Q-GEMM)
    char* ws = (char*)d_ws;
    bf16* lnq  = (bf16*)ws; ws += (size_t)M_ * D_ * 2;
    bf16* lnk  = (bf16*)ws; ws += (size_t)M_ * D_ * 2;
    bf16* lnv  = (bf16*)ws; ws += (size_t)M_ * D_ * 2;
    bf16* wqt  = (bf16*)ws; ws += (size_t)1024 * 1024 * 2;
    bf16* wkt  = (bf16*)ws; ws += (size_t)1024 * 1024 * 2;
    bf16* wvt  = (bf16*)ws; ws += (size_t)1024 * 1024 * 2;
    bf16* wot  = (bf16*)ws; ws += (size_t)1024 * 1024 * 2;
    bf16* Qh   = (bf16*)ws; ws += (size_t)M_ * D_ * 2;   // [B][H][T][DH]
    bf16* Kh   = (bf16*)ws; ws += (size_t)M_ * D_ * 2;
    bf16* Vh   = (bf16*)ws; ws += (size_t)M_ * D_ * 2;
    bf16* Obuf = (bf16*)ws; ws += (size_t)M_ * D_ * 2;   // [B][T][H*DH]
    bf16* VhT  = lnq;                                     // [B][H][DH][T]

    ln_kernel<<<dim3(M_, 3), 256, 0, stream>>>(xq, xk, xv, gamma, beta, lnq, lnk, lnv);
    wconv_kernel<<<dim3(32, 32, 4), 256, 0, stream>>>(Wq, Wk, Wv, Wo, wqt, wkt, wvt, wot);
    gemm_bt<0><<<dim3(8, 32), 256, 0, stream>>>(lnq, wqt, bq, (void*)Qh);
    gemm_bt<0><<<dim3(8, 32), 256, 0, stream>>>(lnk, wkt, bk, (void*)Kh);
    gemm_bt<0><<<dim3(8, 32), 256, 0, stream>>>(lnv, wvt, bv, (void*)Vh);
    vtrans_kernel<<<dim3(T_ / 64, B_ * H_), 256, 0, stream>>>(Vh, VhT);
    attn_kernel<<<dim3(T_ / 64, B_ * H_), 256, 0, stream>>>(Qh, Kh, VhT, lens, attn_out, Obuf);
    gemm_bt<1><<<dim3(8, 32), 256, 0, stream>>>(Obuf, wot, bo, (void*)out);
}

// Round 3
// 742.278 us; speedup vs baseline: 1.1543x; 1.1543x over previous
//
#include <hip/hip_runtime.h>
#include <hip/hip_bf16.h>

// Problem constants
#define B_  2
#define T_  2048
#define D_  1024
#define H_  16
#define DH_ 64
#define M_  (B_*T_)      // 4096 rows per projection

typedef __bf16 bf16;
typedef __bf16 bf16x8 __attribute__((ext_vector_type(8)));
typedef __bf16 bf16x4 __attribute__((ext_vector_type(4)));
typedef float  f32x4  __attribute__((ext_vector_type(4)));

// 0.125 (1/sqrt(64)) * log2(e): exp(s*0.125) == exp2(s*SCL2)
#define SCL2 0.18033688011112042f

// async global->LDS, 16B per lane; lds base must be wave-uniform
#define GLD16(g, l) __builtin_amdgcn_global_load_lds( \
    (const __attribute__((address_space(1))) void*)(g), \
    (__attribute__((address_space(3))) void*)(l), 16, 0, 0)

// ---------------------------------------------------------------------------
// LayerNorm: one block per row (1024 floats), 3 sources selected by blockIdx.y
// ---------------------------------------------------------------------------
__global__ __launch_bounds__(256) void ln_kernel(
    const float* __restrict__ xq, const float* __restrict__ xk,
    const float* __restrict__ xv, const float* __restrict__ gamma,
    const float* __restrict__ beta,
    bf16* __restrict__ oq, bf16* __restrict__ ok, bf16* __restrict__ ov)
{
    const int row = blockIdx.x;
    const int sel = blockIdx.y;
    const float* x = (sel == 0 ? xq : sel == 1 ? xk : xv) + (size_t)row * D_;
    bf16*        o = (sel == 0 ? oq : sel == 1 ? ok : ov) + (size_t)row * D_;
    const int tid = threadIdx.x;

    float4 v = *(const float4*)&x[tid * 4];
    float s  = v.x + v.y + v.z + v.w;
    float s2 = v.x*v.x + v.y*v.y + v.z*v.z + v.w*v.w;
    for (int off = 32; off > 0; off >>= 1) {
        s  += __shfl_down(s,  off, 64);
        s2 += __shfl_down(s2, off, 64);
    }
    __shared__ float red[8];
    const int wave = tid >> 6, lane = tid & 63;
    if (lane == 0) { red[wave] = s; red[4 + wave] = s2; }
    __syncthreads();
    s  = red[0] + red[1] + red[2] + red[3];
    s2 = red[4] + red[5] + red[6] + red[7];
    const float mu   = s * (1.0f / D_);
    const float var  = s2 * (1.0f / D_) - mu * mu;
    const float rstd = rsqrtf(var + 1e-5f);

    float4 g  = *(const float4*)&gamma[tid * 4];
    float4 bb = *(const float4*)&beta[tid * 4];
    bf16x4 o4;
    o4[0] = (bf16)((v.x - mu) * rstd * g.x + bb.x);
    o4[1] = (bf16)((v.y - mu) * rstd * g.y + bb.y);
    o4[2] = (bf16)((v.z - mu) * rstd * g.z + bb.z);
    o4[3] = (bf16)((v.w - mu) * rstd * g.w + bb.w);
    *(bf16x4*)&o[tid * 4] = o4;
}

// ---------------------------------------------------------------------------
// Weight convert + transpose: W[k][n] fp32 -> Wt[n][k] bf16 (1024x1024 each)
// ---------------------------------------------------------------------------
__global__ __launch_bounds__(256) void wconv_kernel(
    const float* __restrict__ Wq, const float* __restrict__ Wk,
    const float* __restrict__ Wv, const float* __restrict__ Wo,
    bf16* __restrict__ wqt, bf16* __restrict__ wkt,
    bf16* __restrict__ wvt, bf16* __restrict__ wot)
{
    const float* Ws[4] = {Wq, Wk, Wv, Wo};
    bf16*        Wt[4] = {wqt, wkt, wvt, wot};
    const float* W = Ws[blockIdx.z];
    bf16*        O = Wt[blockIdx.z];
    const int n0 = blockIdx.x * 32, k0 = blockIdx.y * 32;
    __shared__ float tile[32][33];
    const int tid = threadIdx.x;
    #pragma unroll
    for (int i = 0; i < 4; i++) {
        int e = tid + i * 256;
        int r = e >> 5, c = e & 31;
        tile[r][c] = W[(size_t)(k0 + r) * 1024 + n0 + c];
    }
    __syncthreads();
    #pragma unroll
    for (int i = 0; i < 4; i++) {
        int e = tid + i * 256;
        int nr = e >> 5, kc = e & 31;
        O[(size_t)(n0 + nr) * 1024 + k0 + kc] = (bf16)tile[kc][nr];
    }
}

// ---------------------------------------------------------------------------
// V head transpose: Vh [bh][t][dh] -> VhT [bh][dh][t]  (64x64 tiles via LDS)
// ---------------------------------------------------------------------------
__global__ __launch_bounds__(256) void vtrans_kernel(
    const bf16* __restrict__ Vh, bf16* __restrict__ VhT)
{
    const int bh = blockIdx.y, t0 = blockIdx.x * 64;
    const bf16* src = Vh  + (size_t)bh * T_ * DH_;
    bf16*       dst = VhT + (size_t)bh * T_ * DH_;
    __shared__ bf16 tile[64][72];
    const int tid = threadIdx.x;
    const int r = tid >> 3, c8 = (tid & 7) * 8;
    *(bf16x8*)&tile[r][c8]      = *(const bf16x8*)&src[(size_t)(t0 + r) * DH_ + c8];
    *(bf16x8*)&tile[32 + r][c8] = *(const bf16x8*)&src[(size_t)(t0 + 32 + r) * DH_ + c8];
    __syncthreads();
    bf16x8 o0, o1;
    #pragma unroll
    for (int j = 0; j < 8; j++) { o0[j] = tile[c8 + j][r]; o1[j] = tile[c8 + j][32 + r]; }
    *(bf16x8*)&dst[(size_t)r * T_ + t0 + c8]        = o0;
    *(bf16x8*)&dst[(size_t)(32 + r) * T_ + t0 + c8] = o1;
}

// ---------------------------------------------------------------------------
// GEMM: C = A[M,K] @ Bt[N,K]^T + bias.  TM x 128 tiles, K=1024.
// GLD16 staging into XOR-swizzled LDS (unit' = u ^ ((r>>1)&3)) -> 2-way max.
// MODE 0 (TM=128): stacked QKV GEMM, A has 3*4096 rows; third sel = m0>>12
//   picks weight block (Bt + sel*1M), bias (b0p/b1p/b2p) and dest
//   (Cout + sel*M_*D_), output bf16 headed [B][H][T][DH].
// MODE 1 (TM=64): out-proj, fp32 row-major output, bias b0p.
// ---------------------------------------------------------------------------
template <int TM, int MODE>
__global__ __launch_bounds__(256) void gemm_bt(
    const bf16* __restrict__ A, const bf16* __restrict__ BtP,
    const float* __restrict__ b0p, const float* __restrict__ b1p,
    const float* __restrict__ b2p, void* __restrict__ Cout)
{
    __shared__ bf16 sA[TM * 32];
    __shared__ bf16 sB[128 * 32];
    const int tid  = threadIdx.x;
    const int wave = tid >> 6, lane = tid & 63;
    const int quad = lane >> 4, l16 = lane & 15;
    const int m0 = blockIdx.y * TM, n0 = blockIdx.x * 128;
    constexpr int MI = TM / 32;                   // 4 or 2 MFMA rows per wave
    const int wr = (wave >> 1) * (TM / 2), wc = (wave & 1) * 64;

    const int sel = (MODE == 0) ? (m0 >> 12) : 0;
    const bf16* Bt = BtP + (size_t)sel * 1024 * 1024;
    const int mloc = (MODE == 0) ? (m0 & 4095) : m0;

    f32x4 acc[MI][4] = {};
    const int sr = lane >> 2;   // 0..15
    const int su = lane & 3;

    for (int k0 = 0; k0 < 1024; k0 += 32) {
        __syncthreads();
        #pragma unroll
        for (int i2 = 0; i2 < TM / 64; i2++) {
            const int r = i2 * 64 + wave * 16 + sr;
            GLD16(&A[(size_t)(m0 + r) * 1024 + k0 + (su ^ ((r >> 1) & 3)) * 8],
                  &sA[(i2 * 256 + wave * 64) * 8]);
        }
        #pragma unroll
        for (int i2 = 0; i2 < 2; i2++) {
            const int r = i2 * 64 + wave * 16 + sr;
            GLD16(&Bt[(size_t)(n0 + r) * 1024 + k0 + (su ^ ((r >> 1) & 3)) * 8],
                  &sB[(i2 * 256 + wave * 64) * 8]);
        }
        __syncthreads();

        bf16x8 af[MI], bfr[4];
        #pragma unroll
        for (int i = 0; i < MI; i++) {
            const int row = wr + i * 16 + l16;
            af[i] = *(bf16x8*)&sA[(row * 4 + (quad ^ ((row >> 1) & 3))) * 8];
        }
        #pragma unroll
        for (int j = 0; j < 4; j++) {
            const int row = wc + j * 16 + l16;
            bfr[j] = *(bf16x8*)&sB[(row * 4 + (quad ^ ((row >> 1) & 3))) * 8];
        }
        #pragma unroll
        for (int i = 0; i < MI; i++)
            #pragma unroll
            for (int j = 0; j < 4; j++)
                acc[i][j] = __builtin_amdgcn_mfma_f32_16x16x32_bf16(af[i], bfr[j], acc[i][j], 0, 0, 0);
    }

    const float* bias = (MODE == 0) ? (sel == 0 ? b0p : sel == 1 ? b1p : b2p) : b0p;
    #pragma unroll
    for (int i = 0; i < MI; i++) {
        #pragma unroll
        for (int j = 0; j < 4; j++) {
            const int n = n0 + wc + j * 16 + l16;
            const float bia = bias[n];
            #pragma unroll
            for (int r = 0; r < 4; r++) {
                const int m = mloc + wr + i * 16 + quad * 4 + r;
                const float v = acc[i][j][r] + bia;
                if (MODE == 0) {
                    const int b = m >> 11, t = m & 2047, h = n >> 6, dh = n & 63;
                    ((bf16*)Cout)[(size_t)sel * M_ * D_ +
                                  (((size_t)b * H_ + h) * T_ + t) * DH_ + dh] = (bf16)v;
                } else {
                    ((float*)Cout)[(size_t)m * 1024 + n] = v;
                }
            }
        }
    }
}

// ---------------------------------------------------------------------------
// Fused attention. Per 64-query block: two sweeps over valid 64-key tiles.
// K ([t][dh], contiguous 8KB tile) and V^T ([dh][t]) staged via GLD16 into
// XOR-swizzled LDS (unit' = u ^ (r&7)) -> conflict-free-ish ds_read_b128,
// shared by all 4 waves. No max-subtraction (scores O(1)); single cross-lane
// reduction for the denominator.
// ---------------------------------------------------------------------------
__global__ __launch_bounds__(256) void attn_kernel(
    const bf16* __restrict__ Qh, const bf16* __restrict__ Kh,
    const bf16* __restrict__ VhT, const int* __restrict__ lens,
    float* __restrict__ attn_out, bf16* __restrict__ Obuf)
{
    const int bh = blockIdx.y;
    const int b = bh >> 4, h = bh & 15;
    const int bx = blockIdx.x;
    const int q0 = bx * 64;
    const int len = lens[b];
    const bf16* Qp = Qh  + (size_t)bh * T_ * DH_;
    const bf16* Kp = Kh  + (size_t)bh * T_ * DH_;
    const bf16* Vp = VhT + (size_t)bh * T_ * DH_;   // [dh][t]
    float* attnp = attn_out + (size_t)bh * T_ * T_;

    const int tid  = threadIdx.x;
    const int wave = tid >> 6, lane = tid & 63;
    const int quad = lane >> 4, l16 = lane & 15;

    __shared__ bf16 sK[64 * 64];      // swizzled [t][dh] tile
    __shared__ bf16 sV[64 * 64];      // swizzled [dh][t] tile
    __shared__ float Pf[4][16][68];   // per-wave P tile [q][key]

    // Q A-fragments (m=l16, k=quad*8+j), once per block
    const int qrow = q0 + wave * 16 + l16;
    const bf16x8 aq0 = *(const bf16x8*)&Qp[(size_t)qrow * DH_ + quad * 8];
    const bf16x8 aq1 = *(const bf16x8*)&Qp[(size_t)qrow * DH_ + 32 + quad * 8];

    const int jb_hi = min(bx, (len - 1) >> 6);

    // staging lane geometry: unit = i2*256 + wave*64 + lane; r=unit>>3, u=lane&7
    const int sr = lane >> 3;   // 0..7
    const int su = lane & 7;

    float lsum[4] = {0.f, 0.f, 0.f, 0.f};

    // ---------------- Sweep 1: denominators ----------------
    for (int jb = 0; jb <= jb_hi; jb++) {
        __syncthreads();
        #pragma unroll
        for (int i2 = 0; i2 < 2; i2++) {
            const int r = i2 * 32 + wave * 8 + sr;
            GLD16(&Kp[(size_t)(jb * 64 + r) * DH_ + (su ^ (r & 7)) * 8],
                  &sK[(i2 * 256 + wave * 64) * 8]);
        }
        __syncthreads();

        f32x4 sc[4];
        #pragma unroll
        for (int c = 0; c < 4; c++) {
            const int row = c * 16 + l16;
            bf16x8 b0 = *(bf16x8*)&sK[(row * 8 + (quad ^ (row & 7))) * 8];
            bf16x8 b1 = *(bf16x8*)&sK[(row * 8 + ((quad + 4) ^ (row & 7))) * 8];
            f32x4 s = {};
            s = __builtin_amdgcn_mfma_f32_16x16x32_bf16(aq0, b0, s, 0, 0, 0);
            s = __builtin_amdgcn_mfma_f32_16x16x32_bf16(aq1, b1, s, 0, 0, 0);
            sc[c] = s;
        }
        if ((jb < bx) && ((jb + 1) * 64 <= len)) {      // fully valid tile
            #pragma unroll
            for (int c = 0; c < 4; c++)
                #pragma unroll
                for (int r = 0; r < 4; r++)
                    lsum[r] += __builtin_amdgcn_exp2f(sc[c][r] * SCL2);
        } else {                                        // diagonal / length edge
            #pragma unroll
            for (int c = 0; c < 4; c++) {
                const int k_g = jb * 64 + c * 16 + l16;
                #pragma unroll
                for (int r = 0; r < 4; r++) {
                    const int t_g = q0 + wave * 16 + quad * 4 + r;
                    const bool valid = (k_g <= t_g) & (k_g < len);
                    lsum[r] += valid ? __builtin_amdgcn_exp2f(sc[c][r] * SCL2) : 0.0f;
                }
            }
        }
    }
    float linv[4];
    #pragma unroll
    for (int r = 0; r < 4; r++) {
        float v = lsum[r];
        #pragma unroll
        for (int o = 1; o < 16; o <<= 1) v += __shfl_xor(v, o, 16);
        linv[r] = 1.0f / v;
    }

    // ---------------- Sweep 2: attn write + P@V ----------------
    f32x4 oacc[4] = {};
    for (int jb = 0; jb <= jb_hi; jb++) {
        __syncthreads();
        #pragma unroll
        for (int i2 = 0; i2 < 2; i2++) {
            const int r = i2 * 32 + wave * 8 + sr;
            GLD16(&Kp[(size_t)(jb * 64 + r) * DH_ + (su ^ (r & 7)) * 8],
                  &sK[(i2 * 256 + wave * 64) * 8]);
            GLD16(&Vp[(size_t)r * T_ + jb * 64 + (su ^ (r & 7)) * 8],
                  &sV[(i2 * 256 + wave * 64) * 8]);
        }
        __syncthreads();

        f32x4 sc[4];
        #pragma unroll
        for (int c = 0; c < 4; c++) {
            const int row = c * 16 + l16;
            bf16x8 b0 = *(bf16x8*)&sK[(row * 8 + (quad ^ (row & 7))) * 8];
            bf16x8 b1 = *(bf16x8*)&sK[(row * 8 + ((quad + 4) ^ (row & 7))) * 8];
            f32x4 s = {};
            s = __builtin_amdgcn_mfma_f32_16x16x32_bf16(aq0, b0, s, 0, 0, 0);
            s = __builtin_amdgcn_mfma_f32_16x16x32_bf16(aq1, b1, s, 0, 0, 0);
            sc[c] = s;
        }
        const bool fullt = (jb < bx) && ((jb + 1) * 64 <= len);
        #pragma unroll
        for (int c = 0; c < 4; c++) {
            const int k_g = jb * 64 + c * 16 + l16;
            #pragma unroll
            for (int r = 0; r < 4; r++) {
                float p = __builtin_amdgcn_exp2f(sc[c][r] * SCL2) * linv[r];
                if (!fullt) {
                    const int t_g = q0 + wave * 16 + quad * 4 + r;
                    if (!((k_g <= t_g) & (k_g < len))) p = 0.0f;
                }
                Pf[wave][quad * 4 + r][c * 16 + l16] = p;
            }
        }
        asm volatile("s_waitcnt lgkmcnt(0)" ::: "memory");  // wave-local Pf visibility

        #pragma unroll
        for (int ks = 0; ks < 2; ks++) {
            f32x4 p0 = *(f32x4*)&Pf[wave][l16][ks * 32 + quad * 8];
            f32x4 p1 = *(f32x4*)&Pf[wave][l16][ks * 32 + quad * 8 + 4];
            bf16x8 ap;
            ap[0] = (bf16)p0[0]; ap[1] = (bf16)p0[1]; ap[2] = (bf16)p0[2]; ap[3] = (bf16)p0[3];
            ap[4] = (bf16)p1[0]; ap[5] = (bf16)p1[1]; ap[6] = (bf16)p1[2]; ap[7] = (bf16)p1[3];
            #pragma unroll
            for (int c = 0; c < 4; c++) {
                const int row = c * 16 + l16;
                const bf16x8 vb = *(bf16x8*)&sV[(row * 8 + ((ks * 4 + quad) ^ (row & 7))) * 8];
                oacc[c] = __builtin_amdgcn_mfma_f32_16x16x32_bf16(ap, vb, oacc[c], 0, 0, 0);
            }
        }

        // coalesced attn store: 4 instrs x (4 rows x 256B)
        #pragma unroll
        for (int s = 0; s < 4; s++) {
            const int row = s * 4 + (lane >> 4);
            const int c4  = (lane & 15) * 4;
            f32x4 v4 = *(f32x4*)&Pf[wave][row][c4];
            *(f32x4*)&attnp[(size_t)(q0 + wave * 16 + row) * T_ + jb * 64 + c4] = v4;
        }
    }

    // Zero-fill columns beyond the last computed key tile
    const int zc0 = (jb_hi + 1) * 64;
    if (zc0 < T_) {
        const int span4 = (T_ - zc0) >> 2;
        for (int r = 0; r < 16; r++) {
            const size_t rowbase = (size_t)(q0 + wave * 16 + r) * T_ + zc0;
            for (int c4 = lane; c4 < span4; c4 += 64) {
                *(float4*)&attnp[rowbase + (size_t)c4 * 4] = make_float4(0.f, 0.f, 0.f, 0.f);
            }
        }
    }

    // O (bf16) in [b][t][h*64+dh] layout for the output GEMM
    #pragma unroll
    for (int c = 0; c < 4; c++) {
        #pragma unroll
        for (int r = 0; r < 4; r++) {
            const int t_g = q0 + wave * 16 + quad * 4 + r;
            const int dh = c * 16 + l16;
            Obuf[(size_t)(b * T_ + t_g) * 1024 + h * DH_ + dh] = (bf16)oacc[c][r];
        }
    }
}

// ---------------------------------------------------------------------------
extern "C" void kernel_launch(void* const* d_in, const int* in_sizes, int n_in,
                              void* d_out, int out_size, void* d_ws, size_t ws_size,
                              hipStream_t stream)
{
    const float* xq    = (const float*)d_in[0];
    const float* xk    = (const float*)d_in[1];
    const float* xv    = (const float*)d_in[2];
    const int*   lens  = (const int*)d_in[3];
    const float* Wq    = (const float*)d_in[4];
    const float* bq    = (const float*)d_in[5];
    const float* Wk    = (const float*)d_in[6];
    const float* bk    = (const float*)d_in[7];
    const float* Wv    = (const float*)d_in[8];
    const float* bv    = (const float*)d_in[9];
    const float* Wo    = (const float*)d_in[10];
    const float* bo    = (const float*)d_in[11];
    const float* gamma = (const float*)d_in[12];
    const float* beta  = (const float*)d_in[13];

    float* out      = (float*)d_out;
    float* attn_out = out + (size_t)M_ * D_;   // attn_viz region [B*H][T][T]

    // workspace carve-up (64 MB; contiguity of lnq/lnk/lnv, wqt/wkt/wvt and
    // Qh/Kh/Vh is load-bearing for the stacked QKV GEMM)
    char* ws = (char*)d_ws;
    bf16* lnq  = (bf16*)ws; ws += (size_t)M_ * D_ * 2;
    bf16* lnk  = (bf16*)ws; ws += (size_t)M_ * D_ * 2;
    bf16* lnv  = (bf16*)ws; ws += (size_t)M_ * D_ * 2;
    bf16* wqt  = (bf16*)ws; ws += (size_t)1024 * 1024 * 2;
    bf16* wkt  = (bf16*)ws; ws += (size_t)1024 * 1024 * 2;
    bf16* wvt  = (bf16*)ws; ws += (size_t)1024 * 1024 * 2;
    bf16* wot  = (bf16*)ws; ws += (size_t)1024 * 1024 * 2;
    bf16* Qh   = (bf16*)ws; ws += (size_t)M_ * D_ * 2;   // [B][H][T][DH]
    bf16* Kh   = (bf16*)ws; ws += (size_t)M_ * D_ * 2;
    bf16* Vh   = (bf16*)ws; ws += (size_t)M_ * D_ * 2;
    bf16* Obuf = (bf16*)ws; ws += (size_t)M_ * D_ * 2;   // [B][T][H*DH]
    bf16* VhT  = lnq;   // [B][H][DH][T]; lnq/lnk dead after the QKV GEMM

    ln_kernel<<<dim3(M_, 3), 256, 0, stream>>>(xq, xk, xv, gamma, beta, lnq, lnk, lnv);
    wconv_kernel<<<dim3(32, 32, 4), 256, 0, stream>>>(Wq, Wk, Wv, Wo, wqt, wkt, wvt, wot);
    // stacked QKV projection: A = [lnq;lnk;lnv] (12288 x 1024), 768 blocks
    gemm_bt<128, 0><<<dim3(8, 96), 256, 0, stream>>>(lnq, wqt, bq, bk, bv, (void*)Qh);
    vtrans_kernel<<<dim3(T_ / 64, B_ * H_), 256, 0, stream>>>(Vh, VhT);
    attn_kernel<<<dim3(T_ / 64, B_ * H_), 256, 0, stream>>>(Qh, Kh, VhT, lens, attn_out, Obuf);
    // output projection: 64x128 tiles -> 512 blocks (2/CU)
    gemm_bt<64, 1><<<dim3(8, 64), 256, 0, stream>>>(Obuf, wot, bo, bo, bo, (void*)out);
}